// Round 7
// baseline (253.116 us; speedup 1.0000x reference)
//
#include <hip/hip_runtime.h>

// Problem constants (match reference)
#define N_NODES 10000
#define N_EDGES 160000
#define DIM_IN 32
#define DIM_OUT 64
#define DIM_HID 128
#define BOND 13
#define NB 8            // nodes per group (ONE wave per node; 8 waves/block)
#define NGROUPS (N_NODES / NB)   // 1250
#define CAP 96          // per-node edge bucket capacity (deg~Poisson(16); fixed seed)

typedef _Float16 half2_t __attribute__((ext_vector_type(2)));
typedef _Float16 f16x8 __attribute__((ext_vector_type(8)));
typedef float f32x4 __attribute__((ext_vector_type(4)));
typedef unsigned int uint;

static __device__ __forceinline__ uint packh2(float a, float b) {
    half2_t h;
    h.x = (_Float16)a; h.y = (_Float16)b;
    return __builtin_bit_cast(uint, h);
}

// Ph column swizzle: rotate column by (global) k-pair to break bank conflicts
static __device__ __forceinline__ int swz(int o, int kp) { return (o + kp) & 63; }

// per-wave edge scratch, overlaid on this wave's node's 8KB PhH slot after
// pregf load. sizeof = 64+1024+4352 = 5440 B < 8192.
// eids entries are PACKED: (dst << 18) | edge_id  (dst<16384, e<262144).
struct EScr {
    uint     eids[16];
    _Float16 ea16[16][32];    // 1 KB (zeroed ONCE; pad cols never rewritten)
    _Float16 hbuf16[16][136]; // 4.25 KB (136 = 16B-aligned rows + bank shift)
};

// ======================= fused prep kernel =======================
__global__ void prep_kernel(const float* __restrict__ W2, uint4* __restrict__ W2p,
                            const float* __restrict__ W1, uint4* __restrict__ W1p,
                            const int* __restrict__ ei, int* __restrict__ cnt,
                            uint* __restrict__ es,
                            const float* __restrict__ x, const float* __restrict__ root,
                            const float* __restrict__ bias, float* __restrict__ out) {
    int idx = blockIdx.x * 256 + threadIdx.x;  // 2500 blocks -> 640000
    // W2 as MFMA B-fragments: frag f = k*4 + of; lane (q,l15) holds
    // B[i = q*8 + j][col] = W2[k][i*64 + of*16 + l15], j=0..7 as f16x8.
    if (idx < 512 * 64) {
        int f = idx >> 6, lane = idx & 63;
        int k = f >> 2, of = f & 3;
        int q = lane >> 4, l15 = lane & 15;
        const float* base = W2 + k * 2048 + q * 512 + of * 16 + l15;
        uint u0 = packh2(base[0],   base[64]);
        uint u1 = packh2(base[128], base[192]);
        uint u2 = packh2(base[256], base[320]);
        uint u3 = packh2(base[384], base[448]);
        W2p[idx] = make_uint4(u0, u1, u2, u3);
    }
    if (idx < 512) {  // W1 B-frags: lane holds B[k=quad*8+j][col=nh*16+(lane&15)]
        int nh = idx >> 6, lane = idx & 63;
        int quad = lane >> 4, l15 = lane & 15;
        int col = nh * 16 + l15;
        uint u[4];
#pragma unroll
        for (int jp = 0; jp < 4; ++jp) {
            int k0 = quad * 8 + 2 * jp, k1 = k0 + 1;
            float f0 = (k0 < BOND) ? W1[k0 * DIM_HID + col] : 0.f;
            float f1 = (k1 < BOND) ? W1[k1 * DIM_HID + col] : 0.f;
            u[jp] = packh2(f0, f1);
        }
        W1p[idx] = make_uint4(u[0], u[1], u[2], u[3]);
    }
    if (idx < N_NODES * DIM_OUT) {
        int n = idx >> 6, o = idx & 63;
        float r = bias[o];
        const float* xn = x + n * DIM_IN;
#pragma unroll 8
        for (int i = 0; i < DIM_IN; ++i) r += xn[i] * root[i * DIM_OUT + o];
        out[idx] = r;
    }
    if (idx < N_EDGES) {
        int src = ei[idx];
        int dst = ei[N_EDGES + idx];
        int slot = atomicAdd(&cnt[src], 1);
        if (slot < CAP)   // guard: memory-safe always
            es[src * CAP + slot] = ((uint)dst << 18) | (uint)idx;
    }
}

// ======================= phase 1 =======================
// NB=8, 512-thread blocks (8 waves, ONE wave per node), MFMA P-build in two
// half-k rounds over a 64 KB staging buffer (r5 structure -> 2 blocks/CU).
// The (512,4) reg budget of 128 is made to actually FIT by moving W1
// fragments + b1 (wave-invariant, 40 regs) into LDS, read per-tile via
// VOLATILE ds loads (volatile stops LICM from re-hoisting them into
// registers — the r5 spill was exactly this live-set at a 128 cap: VGPR
// 88->64 + 150 MB hidden spill traffic). r6 compile fix: volatile loads are
// SCALAR uint (HIP_vector_type uint4 has no volatile copy ctor). Backend:
// atomicAdd scatter (r0-proven write-through ~40MB; r3 proved atomics
// innocent) with dst packed into the es word.
__global__ __launch_bounds__(512, 4) void phase1_kernel(
    const float* __restrict__ x,
    const float* __restrict__ ea, const uint4* __restrict__ W1p,
    const float* __restrict__ b1, const uint4* __restrict__ W2p,
    const float* __restrict__ b2, const int* __restrict__ cnt,
    const uint* __restrict__ es, float* __restrict__ out)
{
    __shared__ uint  PhH[NB][DIM_HID / 4][DIM_OUT];  // 64 KiB (half-k staging)
    __shared__ uint  w1lds[8][64][4];                // 8 KiB (W1 B-frags, shared)
    __shared__ float b1lds[DIM_HID];                 // 0.5 KiB

    const int t  = threadIdx.x;
    const int o  = t & 63;    // lane
    const int w  = t >> 6;    // wave 0..7
    const int n0 = blockIdx.x * NB;
    const int l15  = o & 15;
    const int quad = o >> 4;
    const int nd = w;         // node 0..7, one wave each

    // one-time: W1 frags + b1 into LDS (shared by all waves)
    if (t < 512) {
        uint4 v = W1p[t];
        w1lds[t >> 6][t & 63][0] = v.x;
        w1lds[t >> 6][t & 63][1] = v.y;
        w1lds[t >> 6][t & 63][2] = v.z;
        w1lds[t >> 6][t & 63][3] = v.w;
    }
    if (t < DIM_HID) b1lds[t] = b1[t];

    // ---- A-frag: rows = 8 nodes (rows 8..15 zero), k-dim = i (32) ----
    f16x8 af;
    {
        uint ua[4];
        const float* xn8 = x + (long)(n0 + l15) * DIM_IN;
#pragma unroll
        for (int jj = 0; jj < 4; ++jj) {
            float a0 = 0.f, a1 = 0.f;
            if (l15 < NB) {
                a0 = xn8[quad * 8 + 2 * jj];
                a1 = xn8[quad * 8 + 2 * jj + 1];
            }
            ua[jj] = packh2(a0, a1);
        }
        af = __builtin_bit_cast(f16x8, make_uint4(ua[0], ua[1], ua[2], ua[3]));
    }

    // ---- P build via MFMA, TWO half-k rounds over the 64 KB staging ----
    // Round h covers k in [h*64, h*64+64): wave w owns of = w&3 (o-quarter)
    // and k-quarter kq = w>>2 within the half. D layout: col = lane&15,
    // row = (lane>>4)*4 + reg (= node).
    f16x8 pregf[16];
#pragma unroll
    for (int h = 0; h < 2; ++h) {
        const int of = w & 3;
        const int kq = w >> 2;
        const int oo = of * 16 + l15;
        const int kbase = h * 64 + kq * 32;
#pragma unroll 2
        for (int m = 0; m < 16; ++m) {
            const int k0 = kbase + 2 * m;
            const uint4 bu0 = W2p[(k0 * 4 + of) * 64 + o];
            const uint4 bu1 = W2p[((k0 + 1) * 4 + of) * 64 + o];
            f32x4 D0 = {0.f, 0.f, 0.f, 0.f};
            f32x4 D1 = {0.f, 0.f, 0.f, 0.f};
            D0 = __builtin_amdgcn_mfma_f32_16x16x32_f16(
                     af, __builtin_bit_cast(f16x8, bu0), D0, 0, 0, 0);
            D1 = __builtin_amdgcn_mfma_f32_16x16x32_f16(
                     af, __builtin_bit_cast(f16x8, bu1), D1, 0, 0, 0);
            if (o < 32) {   // quads 0,1 hold rows 0..7 = our 8 nodes
                const int kpg = (kbase >> 1) + m;        // global k-pair
                const int kpl = kq * 16 + m;             // local slot 0..31
                const int sc = swz(oo, kpg);
#pragma unroll
                for (int r = 0; r < 4; ++r)
                    PhH[quad * 4 + r][kpl][sc] = packh2(D0[r], D1[r]);
            }
        }
        __syncthreads();
        // read this half's pregf: kk = 2h, 2h+1 (B-frag layout; unswizzle)
#pragma unroll
        for (int nt = 0; nt < 4; ++nt)
#pragma unroll
            for (int kh = 0; kh < 2; ++kh) {
                const int kk = 2 * h + kh;
                const int col = nt * 16 + l15;
                const int kpl = kh * 16 + quad * 4;
                const int kpg = h * 32 + kpl;
                uint4 u;
                u.x = PhH[nd][kpl + 0][swz(col, kpg + 0)];
                u.y = PhH[nd][kpl + 1][swz(col, kpg + 1)];
                u.z = PhH[nd][kpl + 2][swz(col, kpg + 2)];
                u.w = PhH[nd][kpl + 3][swz(col, kpg + 3)];
                pregf[nt * 4 + kk] = __builtin_bit_cast(f16x8, u);
            }
        __syncthreads();  // reads done before next round's writes / EScr overlay
    }

    const int n = n0 + nd;

    // qv[nt] = sum_i x[n,i] * b2[i*64 + nt*16 + l15]  (b2 zeros; kept correct)
    float qv[4] = {0.f, 0.f, 0.f, 0.f};
    {
        const float* xn = x + (long)n * DIM_IN;
#pragma unroll 4
        for (int i = 0; i < DIM_IN; ++i) {
            float xv = xn[i];
#pragma unroll
            for (int nt = 0; nt < 4; ++nt)
                qv[nt] += xv * b2[i * DIM_OUT + nt * 16 + l15];
        }
    }

    const int start = n * CAP;
    int deg = cnt[n];
    deg = deg < CAP ? deg : CAP;

    EScr* S = (EScr*)((char*)&PhH[0][0][0] + nd * 8192);  // wave-private 8KB slot

    // zero ea16 ONCE (64 x 16B = all of [16][32]); pad cols 13..31 stay zero.
    ((uint4*)S->ea16)[o] = make_uint4(0u, 0u, 0u, 0u);
    __builtin_amdgcn_wave_barrier();

    const int ntiles = (deg + 15) >> 4;
#pragma unroll 1
    for (int tb = 0; tb < ntiles; ++tb) {
        const int tilebase = tb * 16;
        const int tcnt = (deg - tilebase < 16) ? (deg - tilebase) : 16;
        __builtin_amdgcn_wave_barrier();
        if (o < tcnt)
            S->eids[o] = es[start + tilebase + o];
        __builtin_amdgcn_wave_barrier();
        if (l15 < BOND) {
#pragma unroll
            for (int r = 0; r < 4; ++r) {
                int p = quad + 4 * r;
                if (p < tcnt) {
                    float v = ea[(long)(S->eids[p] & 0x3FFFFu) * BOND + l15];
                    S->ea16[p][l15] = (_Float16)v;
                }
            }
        }
        __builtin_amdgcn_wave_barrier();
        // h = relu(ea @ W1 + b1): A[m=edge=l15][k=quad*8+j], D row=edge col=hid
        // W1 frags/b1 read per-tile from LDS via VOLATILE SCALAR loads
        // (keeps them out of registers; LICM can't hoist volatile)
        const f16x8 aef = *(const f16x8*)&S->ea16[l15][quad * 8];
#pragma unroll
        for (int nh = 0; nh < 8; ++nh) {
            const volatile uint* wp = &w1lds[nh][o][0];
            uint4 wfu;
            wfu.x = wp[0]; wfu.y = wp[1]; wfu.z = wp[2]; wfu.w = wp[3];
            const float b1v = *(volatile const float*)&b1lds[nh * 16 + l15];
            f32x4 hacc = {0.f, 0.f, 0.f, 0.f};
            hacc = __builtin_amdgcn_mfma_f32_16x16x32_f16(
                       aef, __builtin_bit_cast(f16x8, wfu), hacc, 0, 0, 0);
#pragma unroll
            for (int r = 0; r < 4; ++r) {
                float hv = hacc[r] + b1v;
                S->hbuf16[quad * 4 + r][nh * 16 + l15] =
                    (_Float16)(hv > 0.f ? hv : 0.f);
            }
        }
        __builtin_amdgcn_wave_barrier();
        // msg = h @ P: A-frags from hbuf16, B-frags = pregf; D row=edge col=o
        f16x8 hf[4];
#pragma unroll
        for (int kk = 0; kk < 4; ++kk)
            hf[kk] = *(const f16x8*)&S->hbuf16[l15][kk * 32 + quad * 8];
        uint pk[4];
#pragma unroll
        for (int r = 0; r < 4; ++r)
            pk[r] = S->eids[quad * 4 + r];
#pragma unroll
        for (int nt = 0; nt < 4; ++nt) {
            f32x4 acc = {0.f, 0.f, 0.f, 0.f};
#pragma unroll
            for (int kk = 0; kk < 4; ++kk)
                acc = __builtin_amdgcn_mfma_f32_16x16x32_f16(
                          hf[kk], pregf[nt * 4 + kk], acc, 0, 0, 0);
#pragma unroll
            for (int r = 0; r < 4; ++r) {
                if (quad * 4 + r < tcnt)
                    atomicAdd(&out[(long)(pk[r] >> 18) * DIM_OUT + nt * 16 + l15],
                              acc[r] + qv[nt]);
            }
        }
    }
}

// ======================= relu sweep =======================
__global__ __launch_bounds__(256) void relu_kernel(float* __restrict__ out) {
    int idx = blockIdx.x * 256 + threadIdx.x;
    if (idx < N_NODES * DIM_OUT) {
        float v = out[idx];
        out[idx] = v > 0.f ? v : 0.f;
    }
}

// ======================= launch =======================

extern "C" void kernel_launch(void* const* d_in, const int* in_sizes, int n_in,
                              void* d_out, int out_size, void* d_ws, size_t ws_size,
                              hipStream_t stream) {
    const float* x    = (const float*)d_in[0];
    const int*   ei   = (const int*)d_in[1];   // [2, E]: row 0 = src, row 1 = dst
    const float* ea   = (const float*)d_in[2];
    const float* W1   = (const float*)d_in[3];
    const float* b1   = (const float*)d_in[4];
    const float* W2   = (const float*)d_in[5];
    const float* b2   = (const float*)d_in[6];
    const float* root = (const float*)d_in[7];
    const float* bias = (const float*)d_in[8];
    float* out = (float*)d_out;
    char* ws = (char*)d_ws;

    // workspace layout (~4.4 MB)
    int*   cnt = (int*)(ws + 0);           //    40,064 B (per-src edge counts)
    uint*  es  = (uint*)(ws + 40064);      // 3,840,000 B (packed dst<<18|e, CAP=96)
    uint4* W2p = (uint4*)(ws + 3880064);   //   524,288 B (W2 MFMA B-fragments)
    uint4* W1p = (uint4*)(ws + 4404352);   //     8,192 B (W1 MFMA B-fragments)
    // total 4,412,544 B

    hipMemsetAsync(cnt, 0, 40064, stream);
    prep_kernel<<<2500, 256, 0, stream>>>(W2, W2p, W1, W1p, ei, cnt, es,
                                          x, root, bias, out);
    phase1_kernel<<<NGROUPS, 512, 0, stream>>>(x, ea, W1p, b1, W2p, b2,
                                               cnt, es, out);
    relu_kernel<<<2500, 256, 0, stream>>>(out);
}

// Round 8
// 209.146 us; speedup vs baseline: 1.2102x; 1.2102x over previous
//
#include <hip/hip_runtime.h>

// Problem constants (match reference)
#define N_NODES 10000
#define N_EDGES 160000
#define DIM_IN 32
#define DIM_OUT 64
#define DIM_HID 128
#define BOND 13
#define NB 8            // nodes per group (ONE wave per node; 8 waves/block)
#define NGROUPS (N_NODES / NB)   // 1250
#define CAP 96          // per-node edge bucket capacity (deg~Poisson(16); fixed seed)

typedef _Float16 half2_t __attribute__((ext_vector_type(2)));
typedef _Float16 f16x8 __attribute__((ext_vector_type(8)));
typedef float f32x4 __attribute__((ext_vector_type(4)));
typedef unsigned int uint;

static __device__ __forceinline__ uint packh2(float a, float b) {
    half2_t h;
    h.x = (_Float16)a; h.y = (_Float16)b;
    return __builtin_bit_cast(uint, h);
}

// Ph column swizzle: rotate column by (global) k-pair to break bank conflicts
static __device__ __forceinline__ int swz(int o, int kp) { return (o + kp) & 63; }

// per-wave edge scratch, overlaid on this wave's node's 8KB PhH slot after
// pregf load. sizeof = 64+1024+4352 = 5440 B < 8192.
// eids entries are PACKED: (dst << 18) | edge_id  (dst<16384, e<262144).
struct EScr {
    uint     eids[16];
    _Float16 ea16[16][32];    // 1 KB (zeroed ONCE; pad cols never rewritten)
    _Float16 hbuf16[16][136]; // 4.25 KB (136 = 16B-aligned rows + bank shift)
};

// ======================= fused prep kernel =======================
__global__ void prep_kernel(const float* __restrict__ W2, uint4* __restrict__ W2p,
                            const float* __restrict__ W1, uint4* __restrict__ W1p,
                            const int* __restrict__ ei, int* __restrict__ cnt,
                            uint* __restrict__ es,
                            const float* __restrict__ x, const float* __restrict__ root,
                            const float* __restrict__ bias, float* __restrict__ out) {
    int idx = blockIdx.x * 256 + threadIdx.x;  // 2500 blocks -> 640000
    // W2 as MFMA B-fragments: frag f = k*4 + of; lane (q,l15) holds
    // B[i = q*8 + j][col] = W2[k][i*64 + of*16 + l15], j=0..7 as f16x8.
    if (idx < 512 * 64) {
        int f = idx >> 6, lane = idx & 63;
        int k = f >> 2, of = f & 3;
        int q = lane >> 4, l15 = lane & 15;
        const float* base = W2 + k * 2048 + q * 512 + of * 16 + l15;
        uint u0 = packh2(base[0],   base[64]);
        uint u1 = packh2(base[128], base[192]);
        uint u2 = packh2(base[256], base[320]);
        uint u3 = packh2(base[384], base[448]);
        W2p[idx] = make_uint4(u0, u1, u2, u3);
    }
    if (idx < 512) {  // W1 B-frags: lane holds B[k=quad*8+j][col=nh*16+(lane&15)]
        int nh = idx >> 6, lane = idx & 63;
        int quad = lane >> 4, l15 = lane & 15;
        int col = nh * 16 + l15;
        uint u[4];
#pragma unroll
        for (int jp = 0; jp < 4; ++jp) {
            int k0 = quad * 8 + 2 * jp, k1 = k0 + 1;
            float f0 = (k0 < BOND) ? W1[k0 * DIM_HID + col] : 0.f;
            float f1 = (k1 < BOND) ? W1[k1 * DIM_HID + col] : 0.f;
            u[jp] = packh2(f0, f1);
        }
        W1p[idx] = make_uint4(u[0], u[1], u[2], u[3]);
    }
    if (idx < N_NODES * DIM_OUT) {
        int n = idx >> 6, o = idx & 63;
        float r = bias[o];
        const float* xn = x + n * DIM_IN;
#pragma unroll 8
        for (int i = 0; i < DIM_IN; ++i) r += xn[i] * root[i * DIM_OUT + o];
        out[idx] = r;
    }
    if (idx < N_EDGES) {
        int src = ei[idx];
        int dst = ei[N_EDGES + idx];
        int slot = atomicAdd(&cnt[src], 1);
        if (slot < CAP)   // guard: memory-safe always
            es[src * CAP + slot] = ((uint)dst << 18) | (uint)idx;
    }
}

// ======================= phase 1 =======================
// NB=8, 512-thread blocks (8 waves, ONE wave per node), MFMA P-build in two
// half-k rounds over a 64 KB staging buffer -> 2 blocks/CU by LDS.
// LAUNCH BOUNDS: (512, 2). DISCOVERY (r5/r7 post-mortem): hipcc's 2nd arg is
// CUDA-semantics MIN BLOCKS PER CU, not waves/EU. (512,4) meant 4 blocks x 8
// waves = 32 waves/CU = 8 waves/SIMD -> 64-VGPR cap -> forced spills (VGPR
// pinned at 64, +150-290 MB hidden scratch traffic in r5/r7, regardless of
// what was moved to LDS). (512,2) -> 16 waves/CU -> 128-reg cap; the live
// set is ~88 (r4 measured, no spills). w1f/b1 back in REGISTERS (volatile-LDS
// hack reverted — it added 8-way bank conflicts and didn't stop the spills).
// Backend: atomicAdd scatter with dst packed into the es word (no ei gather).
__global__ __launch_bounds__(512, 2) void phase1_kernel(
    const float* __restrict__ x,
    const float* __restrict__ ea, const uint4* __restrict__ W1p,
    const float* __restrict__ b1, const uint4* __restrict__ W2p,
    const float* __restrict__ b2, const int* __restrict__ cnt,
    const uint* __restrict__ es, float* __restrict__ out)
{
    __shared__ uint PhH[NB][DIM_HID / 4][DIM_OUT];  // 64 KiB (half-k staging)

    const int t  = threadIdx.x;
    const int o  = t & 63;    // lane
    const int w  = t >> 6;    // wave 0..7
    const int n0 = blockIdx.x * NB;
    const int l15  = o & 15;
    const int quad = o >> 4;
    const int nd = w;         // node 0..7, one wave each

    // ---- A-frag: rows = 8 nodes (rows 8..15 zero), k-dim = i (32) ----
    f16x8 af;
    {
        uint ua[4];
        const float* xn8 = x + (long)(n0 + l15) * DIM_IN;
#pragma unroll
        for (int jj = 0; jj < 4; ++jj) {
            float a0 = 0.f, a1 = 0.f;
            if (l15 < NB) {
                a0 = xn8[quad * 8 + 2 * jj];
                a1 = xn8[quad * 8 + 2 * jj + 1];
            }
            ua[jj] = packh2(a0, a1);
        }
        af = __builtin_bit_cast(f16x8, make_uint4(ua[0], ua[1], ua[2], ua[3]));
    }

    // ---- P build via MFMA, TWO half-k rounds over the 64 KB staging ----
    // Round h covers k in [h*64, h*64+64): wave w owns of = w&3 (o-quarter)
    // and k-quarter kq = w>>2 within the half. D layout: col = lane&15,
    // row = (lane>>4)*4 + reg (= node).
    f16x8 pregf[16];
#pragma unroll
    for (int h = 0; h < 2; ++h) {
        const int of = w & 3;
        const int kq = w >> 2;
        const int oo = of * 16 + l15;
        const int kbase = h * 64 + kq * 32;
#pragma unroll 2
        for (int m = 0; m < 16; ++m) {
            const int k0 = kbase + 2 * m;
            const uint4 bu0 = W2p[(k0 * 4 + of) * 64 + o];
            const uint4 bu1 = W2p[((k0 + 1) * 4 + of) * 64 + o];
            f32x4 D0 = {0.f, 0.f, 0.f, 0.f};
            f32x4 D1 = {0.f, 0.f, 0.f, 0.f};
            D0 = __builtin_amdgcn_mfma_f32_16x16x32_f16(
                     af, __builtin_bit_cast(f16x8, bu0), D0, 0, 0, 0);
            D1 = __builtin_amdgcn_mfma_f32_16x16x32_f16(
                     af, __builtin_bit_cast(f16x8, bu1), D1, 0, 0, 0);
            if (o < 32) {   // quads 0,1 hold rows 0..7 = our 8 nodes
                const int kpg = (kbase >> 1) + m;        // global k-pair
                const int kpl = kq * 16 + m;             // local slot 0..31
                const int sc = swz(oo, kpg);
#pragma unroll
                for (int r = 0; r < 4; ++r)
                    PhH[quad * 4 + r][kpl][sc] = packh2(D0[r], D1[r]);
            }
        }
        __syncthreads();
        // read this half's pregf: kk = 2h, 2h+1 (B-frag layout; unswizzle)
#pragma unroll
        for (int nt = 0; nt < 4; ++nt)
#pragma unroll
            for (int kh = 0; kh < 2; ++kh) {
                const int kk = 2 * h + kh;
                const int col = nt * 16 + l15;
                const int kpl = kh * 16 + quad * 4;
                const int kpg = h * 32 + kpl;
                uint4 u;
                u.x = PhH[nd][kpl + 0][swz(col, kpg + 0)];
                u.y = PhH[nd][kpl + 1][swz(col, kpg + 1)];
                u.z = PhH[nd][kpl + 2][swz(col, kpg + 2)];
                u.w = PhH[nd][kpl + 3][swz(col, kpg + 3)];
                pregf[nt * 4 + kk] = __builtin_bit_cast(f16x8, u);
            }
        __syncthreads();  // reads done before next round's writes / EScr overlay
    }

    const int n = n0 + nd;

    // qv[nt] = sum_i x[n,i] * b2[i*64 + nt*16 + l15]  (b2 zeros; kept correct)
    float qv[4] = {0.f, 0.f, 0.f, 0.f};
    {
        const float* xn = x + (long)n * DIM_IN;
#pragma unroll 4
        for (int i = 0; i < DIM_IN; ++i) {
            float xv = xn[i];
#pragma unroll
            for (int nt = 0; nt < 4; ++nt)
                qv[nt] += xv * b2[i * DIM_OUT + nt * 16 + l15];
        }
    }

    // W1 B-frags + b1 per-lane columns (one-time, register-resident)
    f16x8 w1f[8];
    float b1v[8];
#pragma unroll
    for (int nh = 0; nh < 8; ++nh) {
        w1f[nh] = __builtin_bit_cast(f16x8, W1p[nh * 64 + o]);
        b1v[nh] = b1[nh * 16 + l15];
    }

    const int start = n * CAP;
    int deg = cnt[n];
    deg = deg < CAP ? deg : CAP;

    EScr* S = (EScr*)((char*)&PhH[0][0][0] + nd * 8192);  // wave-private 8KB slot

    // zero ea16 ONCE (64 x 16B = all of [16][32]); pad cols 13..31 stay zero.
    ((uint4*)S->ea16)[o] = make_uint4(0u, 0u, 0u, 0u);
    __builtin_amdgcn_wave_barrier();

    const int ntiles = (deg + 15) >> 4;
#pragma unroll 1
    for (int tb = 0; tb < ntiles; ++tb) {
        const int tilebase = tb * 16;
        const int tcnt = (deg - tilebase < 16) ? (deg - tilebase) : 16;
        __builtin_amdgcn_wave_barrier();
        if (o < tcnt)
            S->eids[o] = es[start + tilebase + o];
        __builtin_amdgcn_wave_barrier();
        if (l15 < BOND) {
#pragma unroll
            for (int r = 0; r < 4; ++r) {
                int p = quad + 4 * r;
                if (p < tcnt) {
                    float v = ea[(long)(S->eids[p] & 0x3FFFFu) * BOND + l15];
                    S->ea16[p][l15] = (_Float16)v;
                }
            }
        }
        __builtin_amdgcn_wave_barrier();
        // h = relu(ea @ W1 + b1): A[m=edge=l15][k=quad*8+j], D row=edge col=hid
        const f16x8 aef = *(const f16x8*)&S->ea16[l15][quad * 8];
#pragma unroll
        for (int nh = 0; nh < 8; ++nh) {
            f32x4 hacc = {0.f, 0.f, 0.f, 0.f};
            hacc = __builtin_amdgcn_mfma_f32_16x16x32_f16(aef, w1f[nh], hacc, 0, 0, 0);
#pragma unroll
            for (int r = 0; r < 4; ++r) {
                float hv = hacc[r] + b1v[nh];
                S->hbuf16[quad * 4 + r][nh * 16 + l15] =
                    (_Float16)(hv > 0.f ? hv : 0.f);
            }
        }
        __builtin_amdgcn_wave_barrier();
        // msg = h @ P: A-frags from hbuf16, B-frags = pregf; D row=edge col=o
        f16x8 hf[4];
#pragma unroll
        for (int kk = 0; kk < 4; ++kk)
            hf[kk] = *(const f16x8*)&S->hbuf16[l15][kk * 32 + quad * 8];
        uint pk[4];
#pragma unroll
        for (int r = 0; r < 4; ++r)
            pk[r] = S->eids[quad * 4 + r];
#pragma unroll
        for (int nt = 0; nt < 4; ++nt) {
            f32x4 acc = {0.f, 0.f, 0.f, 0.f};
#pragma unroll
            for (int kk = 0; kk < 4; ++kk)
                acc = __builtin_amdgcn_mfma_f32_16x16x32_f16(
                          hf[kk], pregf[nt * 4 + kk], acc, 0, 0, 0);
#pragma unroll
            for (int r = 0; r < 4; ++r) {
                if (quad * 4 + r < tcnt)
                    atomicAdd(&out[(long)(pk[r] >> 18) * DIM_OUT + nt * 16 + l15],
                              acc[r] + qv[nt]);
            }
        }
    }
}

// ======================= relu sweep =======================
__global__ __launch_bounds__(256) void relu_kernel(float* __restrict__ out) {
    int idx = blockIdx.x * 256 + threadIdx.x;
    if (idx < N_NODES * DIM_OUT) {
        float v = out[idx];
        out[idx] = v > 0.f ? v : 0.f;
    }
}

// ======================= launch =======================

extern "C" void kernel_launch(void* const* d_in, const int* in_sizes, int n_in,
                              void* d_out, int out_size, void* d_ws, size_t ws_size,
                              hipStream_t stream) {
    const float* x    = (const float*)d_in[0];
    const int*   ei   = (const int*)d_in[1];   // [2, E]: row 0 = src, row 1 = dst
    const float* ea   = (const float*)d_in[2];
    const float* W1   = (const float*)d_in[3];
    const float* b1   = (const float*)d_in[4];
    const float* W2   = (const float*)d_in[5];
    const float* b2   = (const float*)d_in[6];
    const float* root = (const float*)d_in[7];
    const float* bias = (const float*)d_in[8];
    float* out = (float*)d_out;
    char* ws = (char*)d_ws;

    // workspace layout (~4.4 MB)
    int*   cnt = (int*)(ws + 0);           //    40,064 B (per-src edge counts)
    uint*  es  = (uint*)(ws + 40064);      // 3,840,000 B (packed dst<<18|e, CAP=96)
    uint4* W2p = (uint4*)(ws + 3880064);   //   524,288 B (W2 MFMA B-fragments)
    uint4* W1p = (uint4*)(ws + 4404352);   //     8,192 B (W1 MFMA B-fragments)
    // total 4,412,544 B

    hipMemsetAsync(cnt, 0, 40064, stream);
    prep_kernel<<<2500, 256, 0, stream>>>(W2, W2p, W1, W1p, ei, cnt, es,
                                          x, root, bias, out);
    phase1_kernel<<<NGROUPS, 512, 0, stream>>>(x, ea, W1p, b1, W2p, b2,
                                               cnt, es, out);
    relu_kernel<<<2500, 256, 0, stream>>>(out);
}

// Round 9
// 185.857 us; speedup vs baseline: 1.3619x; 1.1253x over previous
//
#include <hip/hip_runtime.h>

// Problem constants (match reference)
#define N_NODES 10000
#define N_EDGES 160000
#define DIM_IN 32
#define DIM_OUT 64
#define DIM_HID 128
#define BOND 13
#define NB 16           // nodes per group (ONE wave per node; 16 waves/block)
#define NGROUPS (N_NODES / NB)   // 625
#define CAP 96          // per-node edge bucket capacity (deg~Poisson(16); fixed seed)

typedef _Float16 half2_t __attribute__((ext_vector_type(2)));
typedef _Float16 f16x8 __attribute__((ext_vector_type(8)));
typedef float f32x4 __attribute__((ext_vector_type(4)));
typedef unsigned int uint;

static __device__ __forceinline__ uint packh2(float a, float b) {
    half2_t h;
    h.x = (_Float16)a; h.y = (_Float16)b;
    return __builtin_bit_cast(uint, h);
}

// Ph column swizzle: rotate column by (global) k-pair to break bank conflicts
static __device__ __forceinline__ int swz(int o, int kp) { return (o + kp) & 63; }

// per-wave edge scratch, overlaid on this wave's node's 8KB PhH slot after
// pregf load. sizeof = 64+1024+4352 = 5440 B < 8192.
// eids entries are PACKED: (dst << 18) | edge_id  (dst<16384, e<262144).
struct EScr {
    uint     eids[16];
    _Float16 ea16[16][32];    // 1 KB (zeroed ONCE; pad cols never rewritten)
    _Float16 hbuf16[16][136]; // 4.25 KB (136 = 16B-aligned rows + bank shift)
};

// ======================= fused prep kernel =======================
__global__ void prep_kernel(const float* __restrict__ W2, uint4* __restrict__ W2p,
                            const float* __restrict__ W1, uint4* __restrict__ W1p,
                            const int* __restrict__ ei, int* __restrict__ cnt,
                            uint* __restrict__ es,
                            const float* __restrict__ x, const float* __restrict__ root,
                            const float* __restrict__ bias, float* __restrict__ out) {
    int idx = blockIdx.x * 256 + threadIdx.x;  // 2500 blocks -> 640000
    // W2 as MFMA B-fragments: frag f = k*4 + of; lane (q,l15) holds
    // B[i = q*8 + j][col] = W2[k][i*64 + of*16 + l15], j=0..7 as f16x8.
    if (idx < 512 * 64) {
        int f = idx >> 6, lane = idx & 63;
        int k = f >> 2, of = f & 3;
        int q = lane >> 4, l15 = lane & 15;
        const float* base = W2 + k * 2048 + q * 512 + of * 16 + l15;
        uint u0 = packh2(base[0],   base[64]);
        uint u1 = packh2(base[128], base[192]);
        uint u2 = packh2(base[256], base[320]);
        uint u3 = packh2(base[384], base[448]);
        W2p[idx] = make_uint4(u0, u1, u2, u3);
    }
    if (idx < 512) {  // W1 B-frags: lane holds B[k=quad*8+j][col=nh*16+(lane&15)]
        int nh = idx >> 6, lane = idx & 63;
        int quad = lane >> 4, l15 = lane & 15;
        int col = nh * 16 + l15;
        uint u[4];
#pragma unroll
        for (int jp = 0; jp < 4; ++jp) {
            int k0 = quad * 8 + 2 * jp, k1 = k0 + 1;
            float f0 = (k0 < BOND) ? W1[k0 * DIM_HID + col] : 0.f;
            float f1 = (k1 < BOND) ? W1[k1 * DIM_HID + col] : 0.f;
            u[jp] = packh2(f0, f1);
        }
        W1p[idx] = make_uint4(u[0], u[1], u[2], u[3]);
    }
    if (idx < N_NODES * DIM_OUT) {
        int n = idx >> 6, o = idx & 63;
        float r = bias[o];
        const float* xn = x + n * DIM_IN;
#pragma unroll 8
        for (int i = 0; i < DIM_IN; ++i) r += xn[i] * root[i * DIM_OUT + o];
        out[idx] = r;
    }
    if (idx < N_EDGES) {
        int src = ei[idx];
        int dst = ei[N_EDGES + idx];
        int slot = atomicAdd(&cnt[src], 1);
        if (slot < CAP)   // guard: memory-safe always
            es[src * CAP + slot] = ((uint)dst << 18) | (uint)idx;
    }
}

// ======================= phase 1 =======================
// NEW this round: NB=16, 1024-thread blocks (16 waves, ONE wave per node).
// r8 showed residency is REGISTER-capped at ~16 waves/CU (80 VGPR live set;
// 2x8-wave blocks need 640 regs/SIMD > 512), so instead of chasing occupancy
// this halves the per-wave work: the P-build A-fragment's 16 rows are now all
// real nodes (NB=8 wasted rows 8..15 as zero padding -> 2x redundant MFMA),
// giving 32 loads + 32 MFMAs per wave (was 64), all-lane D-writes (no o<32
// divergence), and the W2p L2 stream halves to 625 x 512 KB = 320 MB.
// __launch_bounds__(1024, 1): CUDA semantics (2nd arg = min BLOCKS/CU,
// r5/r7/r8 post-mortems) -> 16 waves/CU mandatory -> 128-reg cap; live set
// ~80 fits with no spills. PhH[16][32][64] = 128 KB half-k staging (2 rounds);
// EScr overlay = 16 waves x 8 KB = exactly 128 KB. 1 block/CU (all regs allow
// anyway). Edge phase unchanged from r8.
__global__ __launch_bounds__(1024, 1) void phase1_kernel(
    const float* __restrict__ x,
    const float* __restrict__ ea, const uint4* __restrict__ W1p,
    const float* __restrict__ b1, const uint4* __restrict__ W2p,
    const float* __restrict__ b2, const int* __restrict__ cnt,
    const uint* __restrict__ es, float* __restrict__ out)
{
    __shared__ uint PhH[NB][DIM_HID / 4][DIM_OUT];  // 128 KiB (half-k staging)

    const int t  = threadIdx.x;
    const int o  = t & 63;    // lane
    const int w  = t >> 6;    // wave 0..15
    const int n0 = blockIdx.x * NB;
    const int l15  = o & 15;
    const int quad = o >> 4;
    const int nd = w;         // node 0..15, one wave each

    // ---- A-frag: rows = 16 nodes (ALL valid), k-dim = i (32) ----
    // A[m=node=l15][k = quad*8 + j]; read x direct from global (L2-hot)
    f16x8 af;
    {
        uint ua[4];
        const float* xn8 = x + (long)(n0 + l15) * DIM_IN;
#pragma unroll
        for (int jj = 0; jj < 4; ++jj)
            ua[jj] = packh2(xn8[quad * 8 + 2 * jj], xn8[quad * 8 + 2 * jj + 1]);
        af = __builtin_bit_cast(f16x8, make_uint4(ua[0], ua[1], ua[2], ua[3]));
    }

    // ---- P build via MFMA, TWO half-k rounds over the 128 KB staging ----
    // Round h covers k in [h*64, h*64+64): wave w owns of = w&3 (o-quarter)
    // and k-slice ks = w>>2 (16 k-values). D layout: col = lane&15,
    // row = (lane>>4)*4 + reg (= node, all 16 valid).
    f16x8 pregf[16];
    const int of = w & 3;
    const int ks = w >> 2;
#pragma unroll
    for (int h = 0; h < 2; ++h) {
        const int oo = of * 16 + l15;
        const int kbase = h * 64 + ks * 16;
#pragma unroll 2
        for (int m = 0; m < 8; ++m) {
            const int k0 = kbase + 2 * m;
            const uint4 bu0 = W2p[(k0 * 4 + of) * 64 + o];
            const uint4 bu1 = W2p[((k0 + 1) * 4 + of) * 64 + o];
            f32x4 D0 = {0.f, 0.f, 0.f, 0.f};
            f32x4 D1 = {0.f, 0.f, 0.f, 0.f};
            D0 = __builtin_amdgcn_mfma_f32_16x16x32_f16(
                     af, __builtin_bit_cast(f16x8, bu0), D0, 0, 0, 0);
            D1 = __builtin_amdgcn_mfma_f32_16x16x32_f16(
                     af, __builtin_bit_cast(f16x8, bu1), D1, 0, 0, 0);
            const int kpg = (kbase >> 1) + m;        // global k-pair 0..63
            const int kpl = kpg & 31;                // local row in this half
            const int sc = swz(oo, kpg);
#pragma unroll
            for (int r = 0; r < 4; ++r)
                PhH[quad * 4 + r][kpl][sc] = packh2(D0[r], D1[r]);
        }
        __syncthreads();
        // read this half's pregf: kk = 2h, 2h+1 (B-frag layout; unswizzle)
#pragma unroll
        for (int nt = 0; nt < 4; ++nt)
#pragma unroll
            for (int kh = 0; kh < 2; ++kh) {
                const int kk = 2 * h + kh;
                const int col = nt * 16 + l15;
                const int kpl = kh * 16 + quad * 4;
                const int kpg = h * 32 + kpl;
                uint4 u;
                u.x = PhH[nd][kpl + 0][swz(col, kpg + 0)];
                u.y = PhH[nd][kpl + 1][swz(col, kpg + 1)];
                u.z = PhH[nd][kpl + 2][swz(col, kpg + 2)];
                u.w = PhH[nd][kpl + 3][swz(col, kpg + 3)];
                pregf[nt * 4 + kk] = __builtin_bit_cast(f16x8, u);
            }
        __syncthreads();  // reads done before next round's writes / EScr overlay
    }

    const int n = n0 + nd;

    // qv[nt] = sum_i x[n,i] * b2[i*64 + nt*16 + l15]  (b2 zeros; kept correct)
    float qv[4] = {0.f, 0.f, 0.f, 0.f};
    {
        const float* xn = x + (long)n * DIM_IN;
#pragma unroll 4
        for (int i = 0; i < DIM_IN; ++i) {
            float xv = xn[i];
#pragma unroll
            for (int nt = 0; nt < 4; ++nt)
                qv[nt] += xv * b2[i * DIM_OUT + nt * 16 + l15];
        }
    }

    // W1 B-frags + b1 per-lane columns (one-time, register-resident)
    f16x8 w1f[8];
    float b1v[8];
#pragma unroll
    for (int nh = 0; nh < 8; ++nh) {
        w1f[nh] = __builtin_bit_cast(f16x8, W1p[nh * 64 + o]);
        b1v[nh] = b1[nh * 16 + l15];
    }

    const int start = n * CAP;
    int deg = cnt[n];
    deg = deg < CAP ? deg : CAP;

    EScr* S = (EScr*)((char*)&PhH[0][0][0] + nd * 8192);  // wave-private 8KB slot

    // zero ea16 ONCE (64 x 16B = all of [16][32]); pad cols 13..31 stay zero.
    ((uint4*)S->ea16)[o] = make_uint4(0u, 0u, 0u, 0u);
    __builtin_amdgcn_wave_barrier();

    const int ntiles = (deg + 15) >> 4;
#pragma unroll 1
    for (int tb = 0; tb < ntiles; ++tb) {
        const int tilebase = tb * 16;
        const int tcnt = (deg - tilebase < 16) ? (deg - tilebase) : 16;
        __builtin_amdgcn_wave_barrier();
        if (o < tcnt)
            S->eids[o] = es[start + tilebase + o];
        __builtin_amdgcn_wave_barrier();
        if (l15 < BOND) {
#pragma unroll
            for (int r = 0; r < 4; ++r) {
                int p = quad + 4 * r;
                if (p < tcnt) {
                    float v = ea[(long)(S->eids[p] & 0x3FFFFu) * BOND + l15];
                    S->ea16[p][l15] = (_Float16)v;
                }
            }
        }
        __builtin_amdgcn_wave_barrier();
        // h = relu(ea @ W1 + b1): A[m=edge=l15][k=quad*8+j], D row=edge col=hid
        const f16x8 aef = *(const f16x8*)&S->ea16[l15][quad * 8];
#pragma unroll
        for (int nh = 0; nh < 8; ++nh) {
            f32x4 hacc = {0.f, 0.f, 0.f, 0.f};
            hacc = __builtin_amdgcn_mfma_f32_16x16x32_f16(aef, w1f[nh], hacc, 0, 0, 0);
#pragma unroll
            for (int r = 0; r < 4; ++r) {
                float hv = hacc[r] + b1v[nh];
                S->hbuf16[quad * 4 + r][nh * 16 + l15] =
                    (_Float16)(hv > 0.f ? hv : 0.f);
            }
        }
        __builtin_amdgcn_wave_barrier();
        // msg = h @ P: A-frags from hbuf16, B-frags = pregf; D row=edge col=o
        f16x8 hf[4];
#pragma unroll
        for (int kk = 0; kk < 4; ++kk)
            hf[kk] = *(const f16x8*)&S->hbuf16[l15][kk * 32 + quad * 8];
        uint pk[4];
#pragma unroll
        for (int r = 0; r < 4; ++r)
            pk[r] = S->eids[quad * 4 + r];
#pragma unroll
        for (int nt = 0; nt < 4; ++nt) {
            f32x4 acc = {0.f, 0.f, 0.f, 0.f};
#pragma unroll
            for (int kk = 0; kk < 4; ++kk)
                acc = __builtin_amdgcn_mfma_f32_16x16x32_f16(
                          hf[kk], pregf[nt * 4 + kk], acc, 0, 0, 0);
#pragma unroll
            for (int r = 0; r < 4; ++r) {
                if (quad * 4 + r < tcnt)
                    atomicAdd(&out[(long)(pk[r] >> 18) * DIM_OUT + nt * 16 + l15],
                              acc[r] + qv[nt]);
            }
        }
    }
}

// ======================= relu sweep =======================
__global__ __launch_bounds__(256) void relu_kernel(float* __restrict__ out) {
    int idx = blockIdx.x * 256 + threadIdx.x;
    if (idx < N_NODES * DIM_OUT) {
        float v = out[idx];
        out[idx] = v > 0.f ? v : 0.f;
    }
}

// ======================= launch =======================

extern "C" void kernel_launch(void* const* d_in, const int* in_sizes, int n_in,
                              void* d_out, int out_size, void* d_ws, size_t ws_size,
                              hipStream_t stream) {
    const float* x    = (const float*)d_in[0];
    const int*   ei   = (const int*)d_in[1];   // [2, E]: row 0 = src, row 1 = dst
    const float* ea   = (const float*)d_in[2];
    const float* W1   = (const float*)d_in[3];
    const float* b1   = (const float*)d_in[4];
    const float* W2   = (const float*)d_in[5];
    const float* b2   = (const float*)d_in[6];
    const float* root = (const float*)d_in[7];
    const float* bias = (const float*)d_in[8];
    float* out = (float*)d_out;
    char* ws = (char*)d_ws;

    // workspace layout (~4.4 MB)
    int*   cnt = (int*)(ws + 0);           //    40,064 B (per-src edge counts)
    uint*  es  = (uint*)(ws + 40064);      // 3,840,000 B (packed dst<<18|e, CAP=96)
    uint4* W2p = (uint4*)(ws + 3880064);   //   524,288 B (W2 MFMA B-fragments)
    uint4* W1p = (uint4*)(ws + 4404352);   //     8,192 B (W1 MFMA B-fragments)
    // total 4,412,544 B

    hipMemsetAsync(cnt, 0, 40064, stream);
    prep_kernel<<<2500, 256, 0, stream>>>(W2, W2p, W1, W1p, ei, cnt, es,
                                          x, root, bias, out);
    phase1_kernel<<<NGROUPS, 1024, 0, stream>>>(x, ea, W1p, b1, W2p, b2,
                                                cnt, es, out);
    relu_kernel<<<2500, 256, 0, stream>>>(out);
}

// Round 10
// 170.775 us; speedup vs baseline: 1.4822x; 1.0883x over previous
//
#include <hip/hip_runtime.h>

// Problem constants (match reference)
#define N_NODES 10000
#define N_EDGES 160000
#define DIM_IN 32
#define DIM_OUT 64
#define DIM_HID 128
#define BOND 13
#define NB 16           // nodes per group (ONE wave per node; 16 waves/block)
#define NGROUPS (N_NODES / NB)   // 625
#define CAP 96          // per-node edge bucket capacity (deg~Poisson(16); fixed seed)

typedef _Float16 half2_t __attribute__((ext_vector_type(2)));
typedef _Float16 f16x8 __attribute__((ext_vector_type(8)));
typedef float f32x4 __attribute__((ext_vector_type(4)));
typedef unsigned int uint;

static __device__ __forceinline__ uint packh2(float a, float b) {
    half2_t h;
    h.x = (_Float16)a; h.y = (_Float16)b;
    return __builtin_bit_cast(uint, h);
}

// Ph column swizzle: rotate column by (global) k-pair to break bank conflicts
static __device__ __forceinline__ int swz(int o, int kp) { return (o + kp) & 63; }

// per-wave edge scratch, overlaid on this wave's node's 8KB PhH slot after
// pregf load. sizeof = 64+1024+4352 = 5440 B < 8192.
// eids entries are PACKED: (dst << 18) | edge_id  (dst<16384, e<262144).
struct EScr {
    uint     eids[16];
    _Float16 ea16[16][32];    // 1 KB (zeroed ONCE; pad cols never rewritten)
    _Float16 hbuf16[16][136]; // 4.25 KB (136 = 16B-aligned rows + bank shift)
};

// ======================= fused prep kernel =======================
__global__ void prep_kernel(const float* __restrict__ W2, uint4* __restrict__ W2p,
                            const float* __restrict__ W1, uint4* __restrict__ W1p,
                            const int* __restrict__ ei, int* __restrict__ cnt,
                            uint* __restrict__ es,
                            const float* __restrict__ x, const float* __restrict__ root,
                            const float* __restrict__ bias, float* __restrict__ out) {
    int idx = blockIdx.x * 256 + threadIdx.x;  // 2500 blocks -> 640000
    // W2 as MFMA B-fragments: frag f = k*4 + of; lane (q,l15) holds
    // B[i = q*8 + j][col] = W2[k][i*64 + of*16 + l15], j=0..7 as f16x8.
    if (idx < 512 * 64) {
        int f = idx >> 6, lane = idx & 63;
        int k = f >> 2, of = f & 3;
        int q = lane >> 4, l15 = lane & 15;
        const float* base = W2 + k * 2048 + q * 512 + of * 16 + l15;
        uint u0 = packh2(base[0],   base[64]);
        uint u1 = packh2(base[128], base[192]);
        uint u2 = packh2(base[256], base[320]);
        uint u3 = packh2(base[384], base[448]);
        W2p[idx] = make_uint4(u0, u1, u2, u3);
    }
    if (idx < 512) {  // W1 B-frags: lane holds B[k=quad*8+j][col=nh*16+(lane&15)]
        int nh = idx >> 6, lane = idx & 63;
        int quad = lane >> 4, l15 = lane & 15;
        int col = nh * 16 + l15;
        uint u[4];
#pragma unroll
        for (int jp = 0; jp < 4; ++jp) {
            int k0 = quad * 8 + 2 * jp, k1 = k0 + 1;
            float f0 = (k0 < BOND) ? W1[k0 * DIM_HID + col] : 0.f;
            float f1 = (k1 < BOND) ? W1[k1 * DIM_HID + col] : 0.f;
            u[jp] = packh2(f0, f1);
        }
        W1p[idx] = make_uint4(u[0], u[1], u[2], u[3]);
    }
    if (idx < N_NODES * DIM_OUT) {
        int n = idx >> 6, o = idx & 63;
        float r = bias[o];
        const float* xn = x + n * DIM_IN;
#pragma unroll 8
        for (int i = 0; i < DIM_IN; ++i) r += xn[i] * root[i * DIM_OUT + o];
        out[idx] = r;
    }
    if (idx < N_EDGES) {
        int src = ei[idx];
        int dst = ei[N_EDGES + idx];
        int slot = atomicAdd(&cnt[src], 1);
        if (slot < CAP)   // guard: memory-safe always
            es[src * CAP + slot] = ((uint)dst << 18) | (uint)idx;
    }
}

// ======================= phase 1 =======================
// NB=16, 1024-thread blocks (16 waves, ONE wave per node), r9 structure.
// NEW this round (r9 post-mortem: VGPR pinned at 64 + 75 MB spill traffic —
// the allocator optimized for 8 waves/EU occupancy that the 128 KB LDS makes
// unreachable):
//  (1) amdgpu_waves_per_eu(4,4): the REAL budget knob. 4 waves/EU (= what a
//      16-wave 1-block/CU kernel actually runs) -> 512/4 = 128-reg cap.
//  (2) w1f (32 wave-invariant regs) moved to an 8 KB LDS table, re-read per
//      tile as 8x ds_read_b128. LICM would hoist the invariant loads back
//      into registers, so the loop indexes through an asm-laundered zero
//      offset (opaque to the compiler, free at runtime).
// Remaining peak live set ~110 < 128 -> no spills. LDS 136 KB (1 block/CU,
// which registers mandate anyway).
__global__ __launch_bounds__(1024)
__attribute__((amdgpu_waves_per_eu(4, 4)))
void phase1_kernel(
    const float* __restrict__ x,
    const float* __restrict__ ea, const uint4* __restrict__ W1p,
    const float* __restrict__ b1, const uint4* __restrict__ W2p,
    const float* __restrict__ b2, const int* __restrict__ cnt,
    const uint* __restrict__ es, float* __restrict__ out)
{
    __shared__ uint  PhH[NB][DIM_HID / 4][DIM_OUT];  // 128 KiB (half-k staging)
    __shared__ uint4 w1lds[8][64];                   // 8 KiB (W1 B-frags, shared)

    const int t  = threadIdx.x;
    const int o  = t & 63;    // lane
    const int w  = t >> 6;    // wave 0..15
    const int n0 = blockIdx.x * NB;
    const int l15  = o & 15;
    const int quad = o >> 4;
    const int nd = w;         // node 0..15, one wave each

    // one-time: W1 frags into LDS (shared by all waves; sync'd by P-build)
    if (t < 512) w1lds[t >> 6][t & 63] = W1p[t];

    // ---- A-frag: rows = 16 nodes (ALL valid), k-dim = i (32) ----
    // A[m=node=l15][k = quad*8 + j]; read x direct from global (L2-hot)
    f16x8 af;
    {
        uint ua[4];
        const float* xn8 = x + (long)(n0 + l15) * DIM_IN;
#pragma unroll
        for (int jj = 0; jj < 4; ++jj)
            ua[jj] = packh2(xn8[quad * 8 + 2 * jj], xn8[quad * 8 + 2 * jj + 1]);
        af = __builtin_bit_cast(f16x8, make_uint4(ua[0], ua[1], ua[2], ua[3]));
    }

    // ---- P build via MFMA, TWO half-k rounds over the 128 KB staging ----
    // Round h covers k in [h*64, h*64+64): wave w owns of = w&3 (o-quarter)
    // and k-slice ks = w>>2 (16 k-values). D layout: col = lane&15,
    // row = (lane>>4)*4 + reg (= node, all 16 valid).
    f16x8 pregf[16];
    const int of = w & 3;
    const int ks = w >> 2;
#pragma unroll
    for (int h = 0; h < 2; ++h) {
        const int oo = of * 16 + l15;
        const int kbase = h * 64 + ks * 16;
#pragma unroll 2
        for (int m = 0; m < 8; ++m) {
            const int k0 = kbase + 2 * m;
            const uint4 bu0 = W2p[(k0 * 4 + of) * 64 + o];
            const uint4 bu1 = W2p[((k0 + 1) * 4 + of) * 64 + o];
            f32x4 D0 = {0.f, 0.f, 0.f, 0.f};
            f32x4 D1 = {0.f, 0.f, 0.f, 0.f};
            D0 = __builtin_amdgcn_mfma_f32_16x16x32_f16(
                     af, __builtin_bit_cast(f16x8, bu0), D0, 0, 0, 0);
            D1 = __builtin_amdgcn_mfma_f32_16x16x32_f16(
                     af, __builtin_bit_cast(f16x8, bu1), D1, 0, 0, 0);
            const int kpg = (kbase >> 1) + m;        // global k-pair 0..63
            const int kpl = kpg & 31;                // local row in this half
            const int sc = swz(oo, kpg);
#pragma unroll
            for (int r = 0; r < 4; ++r)
                PhH[quad * 4 + r][kpl][sc] = packh2(D0[r], D1[r]);
        }
        __syncthreads();
        // read this half's pregf: kk = 2h, 2h+1 (B-frag layout; unswizzle)
#pragma unroll
        for (int nt = 0; nt < 4; ++nt)
#pragma unroll
            for (int kh = 0; kh < 2; ++kh) {
                const int kk = 2 * h + kh;
                const int col = nt * 16 + l15;
                const int kpl = kh * 16 + quad * 4;
                const int kpg = h * 32 + kpl;
                uint4 u;
                u.x = PhH[nd][kpl + 0][swz(col, kpg + 0)];
                u.y = PhH[nd][kpl + 1][swz(col, kpg + 1)];
                u.z = PhH[nd][kpl + 2][swz(col, kpg + 2)];
                u.w = PhH[nd][kpl + 3][swz(col, kpg + 3)];
                pregf[nt * 4 + kk] = __builtin_bit_cast(f16x8, u);
            }
        __syncthreads();  // reads done before next round's writes / EScr overlay
    }

    const int n = n0 + nd;

    // qv[nt] = sum_i x[n,i] * b2[i*64 + nt*16 + l15]  (b2 zeros; kept correct)
    float qv[4] = {0.f, 0.f, 0.f, 0.f};
    {
        const float* xn = x + (long)n * DIM_IN;
#pragma unroll 4
        for (int i = 0; i < DIM_IN; ++i) {
            float xv = xn[i];
#pragma unroll
            for (int nt = 0; nt < 4; ++nt)
                qv[nt] += xv * b2[i * DIM_OUT + nt * 16 + l15];
        }
    }

    // b1 per-lane columns (8 regs, cheap; W1 frags stay in LDS)
    float b1v[8];
#pragma unroll
    for (int nh = 0; nh < 8; ++nh) b1v[nh] = b1[nh * 16 + l15];

    const int start = n * CAP;
    int deg = cnt[n];
    deg = deg < CAP ? deg : CAP;

    EScr* S = (EScr*)((char*)&PhH[0][0][0] + nd * 8192);  // wave-private 8KB slot

    // zero ea16 ONCE (64 x 16B = all of [16][32]); pad cols 13..31 stay zero.
    ((uint4*)S->ea16)[o] = make_uint4(0u, 0u, 0u, 0u);
    __builtin_amdgcn_wave_barrier();

    const int ntiles = (deg + 15) >> 4;
#pragma unroll 1
    for (int tb = 0; tb < ntiles; ++tb) {
        const int tilebase = tb * 16;
        const int tcnt = (deg - tilebase < 16) ? (deg - tilebase) : 16;
        __builtin_amdgcn_wave_barrier();
        if (o < tcnt)
            S->eids[o] = es[start + tilebase + o];
        __builtin_amdgcn_wave_barrier();
        if (l15 < BOND) {
#pragma unroll
            for (int r = 0; r < 4; ++r) {
                int p = quad + 4 * r;
                if (p < tcnt) {
                    float v = ea[(long)(S->eids[p] & 0x3FFFFu) * BOND + l15];
                    S->ea16[p][l15] = (_Float16)v;
                }
            }
        }
        __builtin_amdgcn_wave_barrier();
        // h = relu(ea @ W1 + b1): A[m=edge=l15][k=quad*8+j], D row=edge col=hid
        // W1 frags re-read from LDS EVERY tile: the index goes through an
        // asm-laundered zero offset so LICM cannot hoist the loads back into
        // registers (that hoist was r9's 75 MB spill).
        uint woff = 0;
        asm volatile("" : "+v"(woff));          // opaque 0: defeats LICM
        const int wo = (o + (int)woff) & 63;
        const f16x8 aef = *(const f16x8*)&S->ea16[l15][quad * 8];
#pragma unroll
        for (int nh = 0; nh < 8; ++nh) {
            const f16x8 wf = __builtin_bit_cast(f16x8, w1lds[nh][wo]);
            f32x4 hacc = {0.f, 0.f, 0.f, 0.f};
            hacc = __builtin_amdgcn_mfma_f32_16x16x32_f16(aef, wf, hacc, 0, 0, 0);
#pragma unroll
            for (int r = 0; r < 4; ++r) {
                float hv = hacc[r] + b1v[nh];
                S->hbuf16[quad * 4 + r][nh * 16 + l15] =
                    (_Float16)(hv > 0.f ? hv : 0.f);
            }
        }
        __builtin_amdgcn_wave_barrier();
        // msg = h @ P: A-frags from hbuf16, B-frags = pregf; D row=edge col=o
        f16x8 hf[4];
#pragma unroll
        for (int kk = 0; kk < 4; ++kk)
            hf[kk] = *(const f16x8*)&S->hbuf16[l15][kk * 32 + quad * 8];
        uint pk[4];
#pragma unroll
        for (int r = 0; r < 4; ++r)
            pk[r] = S->eids[quad * 4 + r];
#pragma unroll
        for (int nt = 0; nt < 4; ++nt) {
            f32x4 acc = {0.f, 0.f, 0.f, 0.f};
#pragma unroll
            for (int kk = 0; kk < 4; ++kk)
                acc = __builtin_amdgcn_mfma_f32_16x16x32_f16(
                          hf[kk], pregf[nt * 4 + kk], acc, 0, 0, 0);
#pragma unroll
            for (int r = 0; r < 4; ++r) {
                if (quad * 4 + r < tcnt)
                    atomicAdd(&out[(long)(pk[r] >> 18) * DIM_OUT + nt * 16 + l15],
                              acc[r] + qv[nt]);
            }
        }
    }
}

// ======================= relu sweep =======================
__global__ __launch_bounds__(256) void relu_kernel(float* __restrict__ out) {
    int idx = blockIdx.x * 256 + threadIdx.x;
    if (idx < N_NODES * DIM_OUT) {
        float v = out[idx];
        out[idx] = v > 0.f ? v : 0.f;
    }
}

// ======================= launch =======================

extern "C" void kernel_launch(void* const* d_in, const int* in_sizes, int n_in,
                              void* d_out, int out_size, void* d_ws, size_t ws_size,
                              hipStream_t stream) {
    const float* x    = (const float*)d_in[0];
    const int*   ei   = (const int*)d_in[1];   // [2, E]: row 0 = src, row 1 = dst
    const float* ea   = (const float*)d_in[2];
    const float* W1   = (const float*)d_in[3];
    const float* b1   = (const float*)d_in[4];
    const float* W2   = (const float*)d_in[5];
    const float* b2   = (const float*)d_in[6];
    const float* root = (const float*)d_in[7];
    const float* bias = (const float*)d_in[8];
    float* out = (float*)d_out;
    char* ws = (char*)d_ws;

    // workspace layout (~4.4 MB)
    int*   cnt = (int*)(ws + 0);           //    40,064 B (per-src edge counts)
    uint*  es  = (uint*)(ws + 40064);      // 3,840,000 B (packed dst<<18|e, CAP=96)
    uint4* W2p = (uint4*)(ws + 3880064);   //   524,288 B (W2 MFMA B-fragments)
    uint4* W1p = (uint4*)(ws + 4404352);   //     8,192 B (W1 MFMA B-fragments)
    // total 4,412,544 B

    hipMemsetAsync(cnt, 0, 40064, stream);
    prep_kernel<<<2500, 256, 0, stream>>>(W2, W2p, W1, W1p, ei, cnt, es,
                                          x, root, bias, out);
    phase1_kernel<<<NGROUPS, 1024, 0, stream>>>(x, ea, W1p, b1, W2p, b2,
                                                cnt, es, out);
    relu_kernel<<<2500, 256, 0, stream>>>(out);
}